// Round 11
// baseline (379.566 us; speedup 1.0000x reference)
//
#include <hip/hip_runtime.h>
#include <hip/hip_bf16.h>
#include <cstdint>
#include <cstddef>

#define M_DIM 8192
#define K_DIM 4096
#define N_DIM 4096
#define EPS 1e-5f

typedef __bf16 bf16x8 __attribute__((ext_vector_type(8)));
typedef unsigned short u16x8 __attribute__((ext_vector_type(8)));
typedef float f32x4 __attribute__((ext_vector_type(4)));

// ---------- helpers ----------

__device__ __forceinline__ unsigned short f2bf(float f) {
  unsigned int u = __builtin_bit_cast(unsigned int, f);
  u += 0x7fffu + ((u >> 16) & 1u);   // round-to-nearest-even
  return (unsigned short)(u >> 16);
}

// GELU(tanh-approx)+ReLU via identity 0.5y(1+tanh(w)) = y*sigmoid(2w):
// ge = y / (1 + exp2(-c2*z)), z = y + 0.044715 y^3, c2 = 2*0.7978845608*log2(e)
__device__ __forceinline__ float fused_epilogue(float acc, float inv, float shift) {
  float y = fmaf(acc, inv, shift);
  float y2 = y * y;
  float z = fmaf(0.044715f * y2, y, y);
  float e = __builtin_amdgcn_exp2f(-2.3022081f * z);
  float ge = y * __builtin_amdgcn_rcpf(1.0f + e);
  return fmaxf(ge, 0.0f);
}

__device__ __forceinline__ void gload_lds16(const void* gsrc, void* ldst) {
  __builtin_amdgcn_global_load_lds(
      (const __attribute__((address_space(1))) void*)gsrc,
      (__attribute__((address_space(3))) void*)ldst,
      16, 0, 0);
}

// ---------- pre-pass: fp32 -> bf16 conversions ----------

__global__ __launch_bounds__(256) void cvt_x_kernel(const float* __restrict__ x,
                                                    unsigned short* __restrict__ xb) {
  size_t i = ((size_t)blockIdx.x * 256 + threadIdx.x) * 8;
  float4 a = *reinterpret_cast<const float4*>(x + i);
  float4 b = *reinterpret_cast<const float4*>(x + i + 4);
  u16x8 o;
  o[0] = f2bf(a.x); o[1] = f2bf(a.y); o[2] = f2bf(a.z); o[3] = f2bf(a.w);
  o[4] = f2bf(b.x); o[5] = f2bf(b.y); o[6] = f2bf(b.z); o[7] = f2bf(b.w);
  *reinterpret_cast<u16x8*>(xb + i) = o;
}

// W [K][N] fp32 -> Wt [N][K] bf16 (transpose + convert)
__global__ __launch_bounds__(256) void cvt_w_transpose(const float* __restrict__ W,
                                                       unsigned short* __restrict__ Wt) {
  __shared__ float tile[32][33];
  const int tx = threadIdx.x & 31;
  const int tg = threadIdx.x >> 5;
  const int n0 = blockIdx.x * 32;
  const int k0 = blockIdx.y * 32;
#pragma unroll
  for (int j = 0; j < 4; ++j) {
    int k = tg * 4 + j;
    tile[k][tx] = W[(size_t)(k0 + k) * N_DIM + n0 + tx];
  }
  __syncthreads();
#pragma unroll
  for (int j = 0; j < 4; ++j) {
    int n = tg * 4 + j;
    Wt[(size_t)(n0 + n) * K_DIM + k0 + tx] = f2bf(tile[tx][n]);
  }
}

// ---------- main GEMM: 256x256 tile, BK=32, 8 waves, ring-3 + read-prefetch ----------
// A [M][K] bf16, Bt [N][K] bf16. LDS: 3 slots/operand (A 3x16 KiB @0, B 3x16 KiB
// @24576 u16) = 96 KiB. Per K-tile tau:
//   top:   stage tile tau+2 -> slot (tau+2)%3   (4 gload_lds, 16B)
//   then:  12 ds_reads for tile tau+1 from slot (tau+1)%3   [data landed AND
//          confirmed (vmcnt(0)+barrier) at end of tau-1 -> full-tile slack]
//   then:  32 MFMA on fragments read during tau-1 (lgkm long satisfied)
//   end:   vmcnt(0) [confirms stage(tau+2); ~1 tile of slack] ; bare s_barrier
// Hazards: stage@tau writes slot(tau-1), whose readers were consumed by
// MFMA(tau-1) before the tau-1 barrier. No lgkmcnt(0) anywhere in the loop.
// Swizzle (bank math): bank = (16*row + 4*c8)%32 -> c8' = c8 ^ ((row>>1)&3)
// covers all 4 c8 per row-parity => 2-way (free). Pre-swizzled global source,
// linear gload_lds dest, swizzled ds_read.

#define STGA(j, S, TT)                                                             \
  gload_lds16(aP + (size_t)(j) * 128 * K_DIM + (size_t)(TT) * 32,                  \
              &lds[(S) * 8192 + (j) * 4096 + tid8])
#define STGB(j, S, TT)                                                             \
  gload_lds16(bP + (size_t)(j) * 128 * K_DIM + (size_t)(TT) * 32,                  \
              &lds[24576 + (S) * 8192 + (j) * 4096 + tid8])

#define LDS_FRAG(off) __builtin_bit_cast(bf16x8, *(const u16x8*)&lds[(off)])

#define KT(T, SW, SR, AC, BC, AR, BR, STG, RD, BAR) do {                           \
  if (STG) { STGA(0, SW, (T) + 2); STGA(1, SW, (T) + 2);                           \
             STGB(0, SW, (T) + 2); STGB(1, SW, (T) + 2); }                         \
  asm volatile("" ::: "memory");                                                   \
  if (RD) {                                                                        \
    _Pragma("unroll") for (int ni = 0; ni < 4; ++ni)                               \
      BR[ni] = LDS_FRAG(24576 + (SR) * 8192 + bBase + ni * 512);                   \
    _Pragma("unroll") for (int mi = 0; mi < 8; ++mi)                               \
      AR[mi] = LDS_FRAG((SR) * 8192 + aBase + mi * 512);                           \
  }                                                                                \
  __builtin_amdgcn_s_setprio(1);                                                   \
  _Pragma("unroll") for (int mi = 0; mi < 8; ++mi)                                 \
  _Pragma("unroll") for (int ni = 0; ni < 4; ++ni)                                 \
    acc[mi][ni] = __builtin_amdgcn_mfma_f32_16x16x32_bf16(AC[mi], BC[ni],          \
                                                          acc[mi][ni], 0, 0, 0);   \
  __builtin_amdgcn_s_setprio(0);                                                   \
  if (BAR) {                                                                       \
    asm volatile("s_waitcnt vmcnt(0)" ::: "memory");                               \
    __builtin_amdgcn_s_barrier();                                                  \
  }                                                                                \
} while (0)

__global__ __launch_bounds__(512, 2) void gemm_bf16_fused(
    const unsigned short* __restrict__ A,
    const unsigned short* __restrict__ Bt,
    const float* __restrict__ gam, const float* __restrict__ bet,
    const float* __restrict__ mu, const float* __restrict__ var,
    float* __restrict__ C) {
  __shared__ __align__(16) unsigned short lds[49152];  // 96 KiB

  const int tid = threadIdx.x;
  const int wave = tid >> 6;
  const int lane = tid & 63;
  const int l15 = lane & 15, l4 = lane >> 4;
  const int wr = wave >> 2, wc = wave & 3;   // 2x4 wave grid; per-wave out 128x64
  const int tid8 = tid * 8;                  // linear gload_lds dest (elem units)

  // XCD-aware swizzle: 512 blocks, 512 % 8 == 0 -> bijective
  const int bid = (int)blockIdx.x;
  const int swz = (bid & 7) * 64 + (bid >> 3);
  const int bx = swz & 15;                   // 16 N-tiles
  const int by = swz >> 4;                   // 32 M-tiles
  const size_t bm = (size_t)by * 256;
  const size_t bn = (size_t)bx * 256;

  // stage source (pre-swizzled global per thread): row = j*128 + (tid>>2),
  // col8_src = (tid&3) ^ ((row>>1)&3) = (tid&3) ^ ((tid>>3)&3)
  const int srow = tid >> 2;
  const int scol = (tid & 3) ^ ((tid >> 3) & 3);
  const unsigned short* aP = A  + (bm + (size_t)srow) * K_DIM + scol * 8;
  const unsigned short* bP = Bt + (bn + (size_t)srow) * K_DIM + scol * 8;

  // ds_read bases (elem units); xk = (l4 ^ ((row>>1)&3))*8, (row>>1)&3 == (l15>>1)&3
  const int xk = (l4 ^ ((l15 >> 1) & 3)) * 8;
  const int aBase = (wr * 128 + l15) * 32 + xk;   // + mi*512
  const int bBase = (wc * 64 + l15) * 32 + xk;    // + ni*512 (within B slot)

  f32x4 acc[8][4] = {};
  bf16x8 a0[8], b0[4], a1[8], b1[4];

  // ---- prologue: stage tiles 0,1 -> slots 0,1; full drain (one-time); reads(0) ----
  STGA(0, 0, 0); STGA(1, 0, 0); STGB(0, 0, 0); STGB(1, 0, 0);
  asm volatile("" ::: "memory");
  STGA(0, 1, 1); STGA(1, 1, 1); STGB(0, 1, 1); STGB(1, 1, 1);
  asm volatile("s_waitcnt vmcnt(0)" ::: "memory");
  __builtin_amdgcn_s_barrier();
#pragma unroll
  for (int ni = 0; ni < 4; ++ni) b0[ni] = LDS_FRAG(24576 + bBase + ni * 512);
#pragma unroll
  for (int mi = 0; mi < 8; ++mi) a0[mi] = LDS_FRAG(aBase + mi * 512);

  // ---- main loop: 128 K-tiles (BK=32); unroll 6 = lcm(3 slots, 2 frag sets) ----
  for (int t = 0; t < 120; t += 6) {
    KT(t + 0, 2, 1, a0, b0, a1, b1, 1, 1, 1);
    KT(t + 1, 0, 2, a1, b1, a0, b0, 1, 1, 1);
    KT(t + 2, 1, 0, a0, b0, a1, b1, 1, 1, 1);
    KT(t + 3, 2, 1, a1, b1, a0, b0, 1, 1, 1);
    KT(t + 4, 0, 2, a0, b0, a1, b1, 1, 1, 1);
    KT(t + 5, 1, 0, a1, b1, a0, b0, 1, 1, 1);
  }
  // ---- tail: tiles 120..127 ----
  KT(120, 2, 1, a0, b0, a1, b1, 1, 1, 1);   // stages 122
  KT(121, 0, 2, a1, b1, a0, b0, 1, 1, 1);   // stages 123
  KT(122, 1, 0, a0, b0, a1, b1, 1, 1, 1);   // stages 124
  KT(123, 2, 1, a1, b1, a0, b0, 1, 1, 1);   // stages 125
  KT(124, 0, 2, a0, b0, a1, b1, 1, 1, 1);   // stages 126
  KT(125, 1, 0, a1, b1, a0, b0, 1, 1, 1);   // stages 127 (slot 1)
  KT(126, 0, 1, a0, b0, a1, b1, 0, 1, 1);   // no stage; reads tile 127 (slot 1)
  KT(127, 0, 0, a1, b1, a0, b0, 0, 0, 0);   // MFMA only

  // ---- epilogue: fused BN + GELU + ReLU ----
  const int row0 = (int)bm + wr * 128;
  const int col0 = (int)bn + wc * 64;
#pragma unroll
  for (int ni = 0; ni < 4; ++ni) {
    const int col = col0 + ni * 16 + l15;
    const float inv = rsqrtf(var[col] + EPS) * gam[col];
    const float shift = fmaf(-mu[col], inv, bet[col]);
#pragma unroll
    for (int mi = 0; mi < 8; ++mi) {
      const int r0 = row0 + mi * 16 + l4 * 4;
#pragma unroll
      for (int r = 0; r < 4; ++r)
        C[(size_t)(r0 + r) * N_DIM + col] = fused_epilogue(acc[mi][ni][r], inv, shift);
    }
  }
}

// ---------- fallback (only if ws too small): fp32 tiled GEMM ----------

__global__ __launch_bounds__(256) void gemm_f32_fallback(
    const float* __restrict__ A, const float* __restrict__ W,
    const float* __restrict__ gam, const float* __restrict__ bet,
    const float* __restrict__ mu, const float* __restrict__ var,
    float* __restrict__ C) {
  __shared__ float As[16][65];
  __shared__ float Bs[16][65];
  const int tid = threadIdx.x;
  const int tx = tid & 15, ty = tid >> 4;
  const int bn0 = blockIdx.x * 64, bm0 = blockIdx.y * 64;
  float acc[4][4] = {};
  for (int k0 = 0; k0 < K_DIM; k0 += 16) {
#pragma unroll
    for (int j = 0; j < 4; ++j)
      As[tid & 15][(tid >> 4) * 4 + j] =
          A[(size_t)(bm0 + (tid >> 4) * 4 + j) * K_DIM + k0 + (tid & 15)];
#pragma unroll
    for (int j = 0; j < 4; ++j)
      Bs[tid >> 4][(tid & 15) * 4 + j] =
          W[(size_t)(k0 + (tid >> 4)) * N_DIM + bn0 + (tid & 15) * 4 + j];
    __syncthreads();
#pragma unroll
    for (int kk = 0; kk < 16; ++kk) {
      float a_[4], b_[4];
#pragma unroll
      for (int i = 0; i < 4; ++i) a_[i] = As[kk][ty * 4 + i];
#pragma unroll
      for (int j = 0; j < 4; ++j) b_[j] = Bs[kk][tx * 4 + j];
#pragma unroll
      for (int i = 0; i < 4; ++i)
#pragma unroll
        for (int j = 0; j < 4; ++j)
          acc[i][j] = fmaf(a_[i], b_[j], acc[i][j]);
    }
    __syncthreads();
  }
#pragma unroll
  for (int j = 0; j < 4; ++j) {
    const int col = bn0 + tx * 4 + j;
    const float inv = rsqrtf(var[col] + EPS) * gam[col];
    const float shift = fmaf(-mu[col], inv, bet[col]);
#pragma unroll
    for (int i = 0; i < 4; ++i) {
      float y = fmaf(acc[i][j], inv, shift);
      float y2 = y * y;
      float z = fmaf(0.044715f * y2, y, y);
      float e = __builtin_amdgcn_exp2f(-2.3022081f * z);
      float ge = y * __builtin_amdgcn_rcpf(1.0f + e);
      C[(size_t)(bm0 + ty * 4 + i) * N_DIM + col] = fmaxf(ge, 0.0f);
    }
  }
}

// ---------- launch ----------

extern "C" void kernel_launch(void* const* d_in, const int* in_sizes, int n_in,
                              void* d_out, int out_size, void* d_ws, size_t ws_size,
                              hipStream_t stream) {
  const float* x  = (const float*)d_in[0];
  const float* w  = (const float*)d_in[1];
  const float* gg = (const float*)d_in[2];
  const float* bb = (const float*)d_in[3];
  const float* mu = (const float*)d_in[4];
  const float* vr = (const float*)d_in[5];
  float* out = (float*)d_out;

  const size_t xb_bytes = (size_t)M_DIM * K_DIM * 2;
  const size_t wt_bytes = (size_t)K_DIM * N_DIM * 2;

  if (ws_size >= xb_bytes + wt_bytes) {
    unsigned short* xb = (unsigned short*)d_ws;
    unsigned short* wt = xb + (size_t)M_DIM * K_DIM;
    cvt_x_kernel<<<dim3((M_DIM * (size_t)K_DIM) / 8 / 256), dim3(256), 0, stream>>>(x, xb);
    cvt_w_transpose<<<dim3(N_DIM / 32, K_DIM / 32), dim3(256), 0, stream>>>(w, wt);
    gemm_bf16_fused<<<dim3((M_DIM / 256) * (N_DIM / 256)), dim3(512), 0, stream>>>(
        xb, wt, gg, bb, mu, vr, out);
  } else {
    gemm_f32_fallback<<<dim3(N_DIM / 64, M_DIM / 64), dim3(256), 0, stream>>>(
        x, w, gg, bb, mu, vr, out);
  }
}